// Round 4
// baseline (436.868 us; speedup 1.0000x reference)
//
#include <hip/hip_runtime.h>
#include <hip/hip_bf16.h>

#define HW    12288
#define Wimg  192
#define Himg  64
#define Wpad  194
#define Ppad  12804   // 66*194

// ---------------------------------------------------------------------------
// K1: deformable gather.  grid = (192 pixel tiles, 4 channel blocks), 256 thr.
// ---------------------------------------------------------------------------
__global__ __launch_bounds__(256) void k_deform(
    const float* __restrict__ x,     // 256 x HW
    const float* __restrict__ xr,    // HW
    const float* __restrict__ rout,  // 256 x 9
    float* __restrict__ y0)          // 256 x HW (fp32)
{
    __shared__ int   s_idx[36][64];  // [k*4+j][pixel]
    __shared__ float s_w[36][64];
    __shared__ float s_r[64][9];     // this block's 64 channels x 9 taps

    const int tile = blockIdx.x;     // 0..191
    const int cblk = blockIdx.y;     // 0..3
    const int tid  = threadIdx.x;
    const int px0  = tile * 64;

    for (int i = tid; i < 64 * 9; i += 256) {
        int cl = i / 9, k = i - cl * 9;
        s_r[cl][k] = rout[(cblk * 64 + cl) * 9 + k];
    }

    for (int item = tid; item < 64 * 9; item += 256) {
        int pl = item / 9, k = item - pl * 9;
        int gp = px0 + pl;
        int h = gp / Wimg, w = gp - h * Wimg;
        int xo = (k % 3) - 1;
        int yo = (k / 3) - 1;
        float off = 3.0f / (1.0f + expf(-xr[gp]));
        float ov  = off * (float)xo;
        int   iv  = yo * Wpad;
        int   pre = (h + 1) * Wpad + (w + 1) + xo + iv;
        float after = (float)(pre + iv) + ov;
        int fl = (int)floorf(ov);
        int ce = (int)ceilf(ov);
        int av_f  = min(max(pre + fl + iv, 0), Ppad - 1);
        int av_f1 = min(max(av_f + xo,    0), Ppad - 1);
        int av_c  = min(max(pre + ce + iv, 0), Ppad - 1);
        int av_c1 = min(max(av_c + xo,    0), Ppad - 1);
        float wf  = fabsf(after - (float)av_f);
        float wf1 = fabsf((float)av_f1 - after);
        float wc1 = fabsf(after - (float)av_c1);
        float wc  = fabsf((float)av_c - after);
        float s1 = wf  * (1.0f / Wpad);
        float s2 = wc1 * (1.0f / Wpad);
        int   idx4[4] = { av_f, av_f1, av_c1, av_c };
        float w4[4]   = { s1 * wf, s1 * wf1, s2 * wc1, s2 * wc };
        #pragma unroll
        for (int j = 0; j < 4; ++j) {
            int av = idx4[j];
            int r  = av / Wpad;
            int cc = av - r * Wpad;
            bool inb = (r >= 1) && (r <= Himg) && (cc >= 1) && (cc <= Wimg);
            s_idx[k * 4 + j][pl] = inb ? ((r - 1) * Wimg + (cc - 1)) : 0;
            s_w[k * 4 + j][pl]   = inb ? w4[j] : 0.0f;
        }
    }
    __syncthreads();

    const int pl    = tid & 63;
    const int clane = tid >> 6;
    const int gp    = px0 + pl;
    for (int i = 0; i < 16; ++i) {
        int cl = clane + 4 * i;
        int c  = cblk * 64 + cl;
        const float* xc = x + (size_t)c * HW;
        float acc = 0.0f;
        #pragma unroll
        for (int k = 0; k < 9; ++k) {
            float part = 0.0f;
            #pragma unroll
            for (int j = 0; j < 4; ++j) {
                part += s_w[k * 4 + j][pl] * xc[s_idx[k * 4 + j][pl]];
            }
            acc += s_r[cl][k] * part;
        }
        y0[(size_t)c * HW + gp] = acc;
    }
}

// ---------------------------------------------------------------------------
// Pointwise GEMM, double-buffered pipeline:
//   Z[128 x HW] = W[128 x CIN] * A[CIN x HW]
// Block = 128 outs x 64 px, grid = 192.  256 threads, each an 8x4 (o,px)
// tile.  Per 16-deep K-chunk: prefetch next chunk's A/W into registers,
// compute current chunk from LDS (512 FMA/thread hides the load latency),
// then ds_write regs -> other LDS buffer, one barrier.  BN partial stats
// (sum, sumsq per channel) fused into the epilogue via atomicAdd.
// ---------------------------------------------------------------------------
template <int CIN>
__global__ __launch_bounds__(256) void k_pw(
    const float* __restrict__ A,     // CIN x HW
    const float* __restrict__ Wt,    // CIN x 128 (transposed weights)
    float* __restrict__ Z,           // 128 x HW
    float* __restrict__ psum)        // 128 x {sum, sumsq}
{
    __shared__ float s_a[2][16][64];
    __shared__ float s_w[2][16][128];
    const int tid = threadIdx.x;
    const int tx  = tid & 15;        // px group (4 px)
    const int ty  = tid >> 4;        // o group (8 outs)
    const int px0 = blockIdx.x * 64;

    const int ar = tid >> 6;         // A staging: rows ar+4i, col ac
    const int ac = tid & 63;
    const int wrr = tid >> 7;        // W staging: rows wrr+2i, col wc
    const int wc  = tid & 127;

    // preload chunk 0
    #pragma unroll
    for (int i = 0; i < 4; ++i)
        s_a[0][ar + 4 * i][ac] = A[(size_t)(ar + 4 * i) * HW + px0 + ac];
    #pragma unroll
    for (int i = 0; i < 8; ++i)
        s_w[0][wrr + 2 * i][wc] = Wt[(size_t)(wrr + 2 * i) * 128 + wc];
    __syncthreads();

    float acc[8][4];
    #pragma unroll
    for (int i = 0; i < 8; ++i)
        #pragma unroll
        for (int j = 0; j < 4; ++j) acc[i][j] = 0.0f;

    float pa[4], pw[8];
    const int NCH = CIN / 16;
    for (int k = 0; k < NCH; ++k) {
        const int buf = k & 1;
        if (k + 1 < NCH) {
            const int cb = (k + 1) * 16;
            #pragma unroll
            for (int i = 0; i < 4; ++i)
                pa[i] = A[(size_t)(cb + ar + 4 * i) * HW + px0 + ac];
            #pragma unroll
            for (int i = 0; i < 8; ++i)
                pw[i] = Wt[(size_t)(cb + wrr + 2 * i) * 128 + wc];
        }
        #pragma unroll
        for (int cc = 0; cc < 16; ++cc) {
            float4 a4  = *(const float4*)&s_a[buf][cc][tx * 4];
            float4 w40 = *(const float4*)&s_w[buf][cc][ty * 8];
            float4 w41 = *(const float4*)&s_w[buf][cc][ty * 8 + 4];
            acc[0][0] += w40.x * a4.x; acc[0][1] += w40.x * a4.y;
            acc[0][2] += w40.x * a4.z; acc[0][3] += w40.x * a4.w;
            acc[1][0] += w40.y * a4.x; acc[1][1] += w40.y * a4.y;
            acc[1][2] += w40.y * a4.z; acc[1][3] += w40.y * a4.w;
            acc[2][0] += w40.z * a4.x; acc[2][1] += w40.z * a4.y;
            acc[2][2] += w40.z * a4.z; acc[2][3] += w40.z * a4.w;
            acc[3][0] += w40.w * a4.x; acc[3][1] += w40.w * a4.y;
            acc[3][2] += w40.w * a4.z; acc[3][3] += w40.w * a4.w;
            acc[4][0] += w41.x * a4.x; acc[4][1] += w41.x * a4.y;
            acc[4][2] += w41.x * a4.z; acc[4][3] += w41.x * a4.w;
            acc[5][0] += w41.y * a4.x; acc[5][1] += w41.y * a4.y;
            acc[5][2] += w41.y * a4.z; acc[5][3] += w41.y * a4.w;
            acc[6][0] += w41.z * a4.x; acc[6][1] += w41.z * a4.y;
            acc[6][2] += w41.z * a4.z; acc[6][3] += w41.z * a4.w;
            acc[7][0] += w41.w * a4.x; acc[7][1] += w41.w * a4.y;
            acc[7][2] += w41.w * a4.z; acc[7][3] += w41.w * a4.w;
        }
        if (k + 1 < NCH) {
            const int nb = buf ^ 1;
            #pragma unroll
            for (int i = 0; i < 4; ++i) s_a[nb][ar + 4 * i][ac] = pa[i];
            #pragma unroll
            for (int i = 0; i < 8; ++i) s_w[nb][wrr + 2 * i][wc] = pw[i];
            __syncthreads();
        }
    }

    #pragma unroll
    for (int i = 0; i < 8; ++i) {
        float4 v = make_float4(acc[i][0], acc[i][1], acc[i][2], acc[i][3]);
        *(float4*)&Z[(size_t)(ty * 8 + i) * HW + px0 + tx * 4] = v;
    }

    // fused BN partial stats: reduce over the 16 tx-lanes of each ty group
    #pragma unroll
    for (int i = 0; i < 8; ++i) {
        float s = acc[i][0] + acc[i][1] + acc[i][2] + acc[i][3];
        float q = acc[i][0] * acc[i][0] + acc[i][1] * acc[i][1]
                + acc[i][2] * acc[i][2] + acc[i][3] * acc[i][3];
        #pragma unroll
        for (int off = 8; off > 0; off >>= 1) {
            s += __shfl_down(s, off, 16);
            q += __shfl_down(q, off, 16);
        }
        if (tx == 0) {
            atomicAdd(&psum[2 * (ty * 8 + i)],     s);
            atomicAdd(&psum[2 * (ty * 8 + i) + 1], q);
        }
    }
}

// ---------------------------------------------------------------------------
// Finalize BN params in place: (sum, sumsq) -> (scale, shift).  1 block.
// ---------------------------------------------------------------------------
__global__ void k_params(float* __restrict__ p,
                         const float* __restrict__ g,
                         const float* __restrict__ b)
{
    const int c = threadIdx.x;   // 128
    float s = p[2 * c], q = p[2 * c + 1];
    float mu  = s * (1.0f / HW);
    float var = q * (1.0f / HW) - mu * mu;
    float sc  = g[c] * rsqrtf(var + 1e-5f);
    p[2 * c]     = sc;
    p[2 * c + 1] = b[c] - mu * sc;
}

// ---------------------------------------------------------------------------
// Zero the three 256-float psum buffers (they sit contiguously).
// ---------------------------------------------------------------------------
__global__ void k_prep(float* __restrict__ p)
{
    for (int i = threadIdx.x; i < 768; i += 256) p[i] = 0.0f;
}

// ---------------------------------------------------------------------------
// Weight transpose: Wt[c][o] = W[o][c].  grid = 128 (one block per out row).
// ---------------------------------------------------------------------------
__global__ void k_tr(const float* __restrict__ W, float* __restrict__ Wt, int Cin)
{
    const int o = blockIdx.x;
    for (int c = threadIdx.x; c < Cin; c += 256)
        Wt[(size_t)c * 128 + o] = W[o * Cin + c];
}

// ---------------------------------------------------------------------------
// Fused BN+LeakyReLU then depthwise 3x3 (pad 1).  One thread / output.
// ---------------------------------------------------------------------------
__global__ __launch_bounds__(256) void k_dw(
    const float* __restrict__ Z,
    const float* __restrict__ params,
    const float* __restrict__ dwgt,  // 128 x 9
    float* __restrict__ D)
{
    const int t = blockIdx.x * 256 + threadIdx.x;
    const int c = t / HW;
    const int p = t - c * HW;
    const int h = p / Wimg;
    const int w = p - h * Wimg;
    const float sc = params[2 * c];
    const float sh = params[2 * c + 1];
    float wk[9];
    #pragma unroll
    for (int k = 0; k < 9; ++k) wk[k] = dwgt[c * 9 + k];
    float acc = 0.0f;
    #pragma unroll
    for (int ky = 0; ky < 3; ++ky) {
        int hh = h + ky - 1;
        if (hh < 0 || hh >= Himg) continue;
        #pragma unroll
        for (int kx = 0; kx < 3; ++kx) {
            int ww = w + kx - 1;
            if (ww < 0 || ww >= Wimg) continue;
            float z = Z[(size_t)c * HW + hh * Wimg + ww];
            float y = z * sc + sh;
            y = (y >= 0.0f) ? y : 0.01f * y;
            acc += wk[ky * 3 + kx] * y;
        }
    }
    D[t] = acc;
}

// ---------------------------------------------------------------------------
// Final BN+LeakyReLU (fp32 out).
// ---------------------------------------------------------------------------
__global__ __launch_bounds__(256) void k_final(
    const float* __restrict__ Z,
    const float* __restrict__ params,
    float* __restrict__ out)
{
    const int t = blockIdx.x * 256 + threadIdx.x;
    const int c = t / HW;
    float v = Z[t] * params[2 * c] + params[2 * c + 1];
    v = (v >= 0.0f) ? v : 0.01f * v;
    out[t] = v;
}

// ---------------------------------------------------------------------------
extern "C" void kernel_launch(void* const* d_in, const int* in_sizes, int n_in,
                              void* d_out, int out_size, void* d_ws, size_t ws_size,
                              hipStream_t stream) {
    const float* x   = (const float*)d_in[0];
    const float* xr  = (const float*)d_in[1];
    const float* ro  = (const float*)d_in[2];
    const float* wr  = (const float*)d_in[3];
    const float* gr  = (const float*)d_in[4];
    const float* br  = (const float*)d_in[5];
    const float* dw1 = (const float*)d_in[6];
    const float* pw1 = (const float*)d_in[7];
    const float* g1  = (const float*)d_in[8];
    const float* b1  = (const float*)d_in[9];
    const float* dw2 = (const float*)d_in[10];
    const float* pw2 = (const float*)d_in[11];
    const float* g2  = (const float*)d_in[12];
    const float* b2  = (const float*)d_in[13];

    float* ws = (float*)d_ws;
    float* A  = ws;
    float* B  = ws + 3145728;
    float* C  = ws + 4718592;
    float* y0 = A;
    float* z1 = B;
    float* d1 = C;
    float* z2 = A;                   // first 1.5M of A
    float* d2 = B;
    float* z3 = A + 1572864;         // second half of A
    float* wrT  = C;                 // 32768 floats, dead before d1 written
    float* pw1T = B;                 // 16384 floats, staged after z1 is dead
    float* pw2T = C;                 // 16384 floats, staged after d1 is dead
    float* p1 = ws + 6291456;
    float* p2 = p1 + 256;
    float* p3 = p2 + 256;
    float* out = (float*)d_out;

    k_prep<<<1, 256, 0, stream>>>(p1);
    k_tr<<<128, 256, 0, stream>>>(wr, wrT, 256);
    k_deform<<<dim3(192, 4), 256, 0, stream>>>(x, xr, ro, y0);
    k_pw<256><<<192, 256, 0, stream>>>(y0, wrT, z1, p1);
    k_params<<<1, 128, 0, stream>>>(p1, gr, br);
    k_dw<<<6144, 256, 0, stream>>>(z1, p1, dw1, d1);
    k_tr<<<128, 256, 0, stream>>>(pw1, pw1T, 128);      // z1 (B) now dead
    k_pw<128><<<192, 256, 0, stream>>>(d1, pw1T, z2, p2);
    k_params<<<1, 128, 0, stream>>>(p2, g1, b1);
    k_dw<<<6144, 256, 0, stream>>>(z2, p2, dw2, d2);    // overwrites pw1T (dead)
    k_tr<<<128, 256, 0, stream>>>(pw2, pw2T, 128);      // d1 (C) now dead
    k_pw<128><<<192, 256, 0, stream>>>(d2, pw2T, z3, p3);
    k_params<<<1, 128, 0, stream>>>(p3, g2, b2);
    k_final<<<6144, 256, 0, stream>>>(z3, p3, out);
}

// Round 5
// 322.528 us; speedup vs baseline: 1.3545x; 1.3545x over previous
//
#include <hip/hip_runtime.h>
#include <hip/hip_bf16.h>

#define HW    12288
#define Wimg  192
#define Himg  64
#define Wpad  194
#define Ppad  12804   // 66*194

// ---------------------------------------------------------------------------
// K1: deformable gather.  grid = (192 px tiles, 8 channel blocks of 32).
// ---------------------------------------------------------------------------
__global__ __launch_bounds__(256) void k_deform(
    const float* __restrict__ x,     // 256 x HW
    const float* __restrict__ xr,    // HW
    const float* __restrict__ rout,  // 256 x 9
    float* __restrict__ y0)          // 256 x HW (fp32)
{
    __shared__ int   s_idx[36][64];  // [k*4+j][pixel]
    __shared__ float s_w[36][64];
    __shared__ float s_r[32][9];     // this block's 32 channels x 9 taps

    const int tile = blockIdx.x;     // 0..191
    const int cblk = blockIdx.y;     // 0..7
    const int tid  = threadIdx.x;
    const int px0  = tile * 64;

    for (int i = tid; i < 32 * 9; i += 256) {
        int cl = i / 9, k = i - cl * 9;
        s_r[cl][k] = rout[(cblk * 32 + cl) * 9 + k];
    }

    for (int item = tid; item < 64 * 9; item += 256) {
        int pl = item / 9, k = item - pl * 9;
        int gp = px0 + pl;
        int h = gp / Wimg, w = gp - h * Wimg;
        int xo = (k % 3) - 1;
        int yo = (k / 3) - 1;
        float off = 3.0f / (1.0f + expf(-xr[gp]));
        float ov  = off * (float)xo;
        int   iv  = yo * Wpad;
        int   pre = (h + 1) * Wpad + (w + 1) + xo + iv;
        float after = (float)(pre + iv) + ov;
        int fl = (int)floorf(ov);
        int ce = (int)ceilf(ov);
        int av_f  = min(max(pre + fl + iv, 0), Ppad - 1);
        int av_f1 = min(max(av_f + xo,    0), Ppad - 1);
        int av_c  = min(max(pre + ce + iv, 0), Ppad - 1);
        int av_c1 = min(max(av_c + xo,    0), Ppad - 1);
        float wf  = fabsf(after - (float)av_f);
        float wf1 = fabsf((float)av_f1 - after);
        float wc1 = fabsf(after - (float)av_c1);
        float wc  = fabsf((float)av_c - after);
        float s1 = wf  * (1.0f / Wpad);
        float s2 = wc1 * (1.0f / Wpad);
        int   idx4[4] = { av_f, av_f1, av_c1, av_c };
        float w4[4]   = { s1 * wf, s1 * wf1, s2 * wc1, s2 * wc };
        #pragma unroll
        for (int j = 0; j < 4; ++j) {
            int av = idx4[j];
            int r  = av / Wpad;
            int cc = av - r * Wpad;
            bool inb = (r >= 1) && (r <= Himg) && (cc >= 1) && (cc <= Wimg);
            s_idx[k * 4 + j][pl] = inb ? ((r - 1) * Wimg + (cc - 1)) : 0;
            s_w[k * 4 + j][pl]   = inb ? w4[j] : 0.0f;
        }
    }
    __syncthreads();

    const int pl    = tid & 63;
    const int clane = tid >> 6;
    const int gp    = px0 + pl;
    for (int i = 0; i < 8; ++i) {
        int cl = clane + 4 * i;          // local channel 0..31
        int c  = cblk * 32 + cl;
        const float* xc = x + (size_t)c * HW;
        float acc = 0.0f;
        #pragma unroll
        for (int k = 0; k < 9; ++k) {
            float part = 0.0f;
            #pragma unroll
            for (int j = 0; j < 4; ++j) {
                part += s_w[k * 4 + j][pl] * xc[s_idx[k * 4 + j][pl]];
            }
            acc += s_r[cl][k] * part;
        }
        y0[(size_t)c * HW + gp] = acc;
    }
}

// ---------------------------------------------------------------------------
// Pointwise GEMM, split-K:  Z[128 x HW] += W[128 x CIN] * A[CIN x HW].
// Block = 64 outs x 64 px x K-half, grid (192, 2, 2).  256 threads, 4x4
// register tile, 32-deep LDS chunks, atomicAdd epilogue into pre-zeroed Z.
// ---------------------------------------------------------------------------
template <int CIN>
__global__ __launch_bounds__(256) void k_pw(
    const float* __restrict__ A,     // CIN x HW
    const float* __restrict__ Wt,    // CIN x 128 (transposed weights)
    float* __restrict__ Z)           // 128 x HW (pre-zeroed)
{
    __shared__ float s_a[32][64];
    __shared__ float s_w[32][64];
    const int tid = threadIdx.x;
    const int tx  = tid & 15;        // px group (4 px)
    const int ty  = tid >> 4;        // o group (4 outs)
    const int px0 = blockIdx.x * 64;
    const int o0  = blockIdx.y * 64;
    const int KH  = CIN / 2;
    const int cb0 = blockIdx.z * KH;

    float acc[4][4];
    #pragma unroll
    for (int i = 0; i < 4; ++i)
        #pragma unroll
        for (int j = 0; j < 4; ++j) acc[i][j] = 0.0f;

    const int sr = tid >> 6;         // staging row base (0..3), rows sr+4i
    const int sc = tid & 63;         // staging col

    for (int cb = cb0; cb < cb0 + KH; cb += 32) {
        #pragma unroll
        for (int i = 0; i < 8; ++i)
            s_a[sr + 4 * i][sc] = A[(size_t)(cb + sr + 4 * i) * HW + px0 + sc];
        #pragma unroll
        for (int i = 0; i < 8; ++i)
            s_w[sr + 4 * i][sc] = Wt[(size_t)(cb + sr + 4 * i) * 128 + o0 + sc];
        __syncthreads();
        #pragma unroll
        for (int cc = 0; cc < 32; ++cc) {
            float4 a4 = *(const float4*)&s_a[cc][tx * 4];
            float4 w4 = *(const float4*)&s_w[cc][ty * 4];
            acc[0][0] += w4.x * a4.x; acc[0][1] += w4.x * a4.y;
            acc[0][2] += w4.x * a4.z; acc[0][3] += w4.x * a4.w;
            acc[1][0] += w4.y * a4.x; acc[1][1] += w4.y * a4.y;
            acc[1][2] += w4.y * a4.z; acc[1][3] += w4.y * a4.w;
            acc[2][0] += w4.z * a4.x; acc[2][1] += w4.z * a4.y;
            acc[2][2] += w4.z * a4.z; acc[2][3] += w4.z * a4.w;
            acc[3][0] += w4.w * a4.x; acc[3][1] += w4.w * a4.y;
            acc[3][2] += w4.w * a4.z; acc[3][3] += w4.w * a4.w;
        }
        __syncthreads();
    }

    #pragma unroll
    for (int i = 0; i < 4; ++i)
        #pragma unroll
        for (int j = 0; j < 4; ++j)
            atomicAdd(&Z[(size_t)(o0 + ty * 4 + i) * HW + px0 + tx * 4 + j],
                      acc[i][j]);
}

// ---------------------------------------------------------------------------
// BN stats: grid = (128 ch x 4 segments).  atomicAdd partial (sum,sumsq).
// ---------------------------------------------------------------------------
__global__ __launch_bounds__(256) void k_stats(
    const float* __restrict__ Z,
    float* __restrict__ psum)        // 128 x {sum,sumsq}, pre-zeroed
{
    __shared__ float s_s[4], s_q[4];
    const int c   = blockIdx.x >> 2;
    const int seg = blockIdx.x & 3;
    const int tid = threadIdx.x;
    const float* p = Z + (size_t)c * HW + seg * 3072;
    float s = 0.0f, q = 0.0f;
    #pragma unroll
    for (int i = 0; i < 12; ++i) {
        float v = p[tid + i * 256];
        s += v;
        q += v * v;
    }
    #pragma unroll
    for (int off = 32; off > 0; off >>= 1) {
        s += __shfl_down(s, off, 64);
        q += __shfl_down(q, off, 64);
    }
    if ((tid & 63) == 0) { s_s[tid >> 6] = s; s_q[tid >> 6] = q; }
    __syncthreads();
    if (tid == 0) {
        s = s_s[0] + s_s[1] + s_s[2] + s_s[3];
        q = s_q[0] + s_q[1] + s_q[2] + s_q[3];
        atomicAdd(&psum[2 * c],     s);
        atomicAdd(&psum[2 * c + 1], q);
    }
}

// ---------------------------------------------------------------------------
// Finalize BN params in place: (sum, sumsq) -> (scale, shift).  1 block.
// ---------------------------------------------------------------------------
__global__ void k_params(float* __restrict__ p,
                         const float* __restrict__ g,
                         const float* __restrict__ b)
{
    const int c = threadIdx.x;   // 128
    float s = p[2 * c], q = p[2 * c + 1];
    float mu  = s * (1.0f / HW);
    float var = q * (1.0f / HW) - mu * mu;
    float sc  = g[c] * rsqrtf(var + 1e-5f);
    p[2 * c]     = sc;
    p[2 * c + 1] = b[c] - mu * sc;
}

// ---------------------------------------------------------------------------
// Weight transpose: Wt[c][o] = W[o][c].  grid = 128.
// ---------------------------------------------------------------------------
__global__ void k_tr(const float* __restrict__ W, float* __restrict__ Wt, int Cin)
{
    const int o = blockIdx.x;
    for (int c = threadIdx.x; c < Cin; c += 256)
        Wt[(size_t)c * 128 + o] = W[o * Cin + c];
}

// ---------------------------------------------------------------------------
// Fused BN+LeakyReLU then depthwise 3x3 (pad 1).  One thread / output.
// ---------------------------------------------------------------------------
__global__ __launch_bounds__(256) void k_dw(
    const float* __restrict__ Z,
    const float* __restrict__ params,
    const float* __restrict__ dwgt,  // 128 x 9
    float* __restrict__ D)
{
    const int t = blockIdx.x * 256 + threadIdx.x;
    const int c = t / HW;
    const int p = t - c * HW;
    const int h = p / Wimg;
    const int w = p - h * Wimg;
    const float sc = params[2 * c];
    const float sh = params[2 * c + 1];
    float wk[9];
    #pragma unroll
    for (int k = 0; k < 9; ++k) wk[k] = dwgt[c * 9 + k];
    float acc = 0.0f;
    #pragma unroll
    for (int ky = 0; ky < 3; ++ky) {
        int hh = h + ky - 1;
        if (hh < 0 || hh >= Himg) continue;
        #pragma unroll
        for (int kx = 0; kx < 3; ++kx) {
            int ww = w + kx - 1;
            if (ww < 0 || ww >= Wimg) continue;
            float z = Z[(size_t)c * HW + hh * Wimg + ww];
            float y = z * sc + sh;
            y = (y >= 0.0f) ? y : 0.01f * y;
            acc += wk[ky * 3 + kx] * y;
        }
    }
    D[t] = acc;
}

// ---------------------------------------------------------------------------
// Final BN+LeakyReLU (fp32 out).
// ---------------------------------------------------------------------------
__global__ __launch_bounds__(256) void k_final(
    const float* __restrict__ Z,
    const float* __restrict__ params,
    float* __restrict__ out)
{
    const int t = blockIdx.x * 256 + threadIdx.x;
    const int c = t / HW;
    float v = Z[t] * params[2 * c] + params[2 * c + 1];
    v = (v >= 0.0f) ? v : 0.01f * v;
    out[t] = v;
}

// ---------------------------------------------------------------------------
extern "C" void kernel_launch(void* const* d_in, const int* in_sizes, int n_in,
                              void* d_out, int out_size, void* d_ws, size_t ws_size,
                              hipStream_t stream) {
    const float* x   = (const float*)d_in[0];
    const float* xr  = (const float*)d_in[1];
    const float* ro  = (const float*)d_in[2];
    const float* wr  = (const float*)d_in[3];
    const float* gr  = (const float*)d_in[4];
    const float* br  = (const float*)d_in[5];
    const float* dw1 = (const float*)d_in[6];
    const float* pw1 = (const float*)d_in[7];
    const float* g1  = (const float*)d_in[8];
    const float* b1  = (const float*)d_in[9];
    const float* dw2 = (const float*)d_in[10];
    const float* pw2 = (const float*)d_in[11];
    const float* g2  = (const float*)d_in[12];
    const float* b2  = (const float*)d_in[13];

    float* ws = (float*)d_ws;
    float* A  = ws;                  // 3,145,728 floats
    float* B  = ws + 3145728;        // 1,572,864
    float* C  = ws + 4718592;        // 1,572,864
    float* y0 = A;
    float* z1 = B;
    float* d1 = C;
    float* z2 = A;                   // first half of A
    float* d2 = B;
    float* z3 = A + 1572864;         // second half of A
    float* wrT  = C;                 // dead before d1 written
    float* pw1T = B;                 // staged after z1 dead
    float* pw2T = C;                 // staged after d1 dead
    float* p1 = ws + 6291456;
    float* p2 = p1 + 256;
    float* p3 = p2 + 256;
    float* out = (float*)d_out;

    hipMemsetAsync(p1, 0, 768 * 4, stream);            // p1,p2,p3
    hipMemsetAsync(z1, 0, 1572864 * 4, stream);        // B slot
    k_tr<<<128, 256, 0, stream>>>(wr, wrT, 256);
    k_deform<<<dim3(192, 8), 256, 0, stream>>>(x, xr, ro, y0);
    k_pw<256><<<dim3(192, 2, 2), 256, 0, stream>>>(y0, wrT, z1);
    hipMemsetAsync(A, 0, 3145728 * 4, stream);         // z2+z3 slots (y0 dead)
    k_stats<<<512, 256, 0, stream>>>(z1, p1);
    k_params<<<1, 128, 0, stream>>>(p1, gr, br);
    k_dw<<<6144, 256, 0, stream>>>(z1, p1, dw1, d1);
    k_tr<<<128, 256, 0, stream>>>(pw1, pw1T, 128);     // z1 (B) dead
    k_pw<128><<<dim3(192, 2, 2), 256, 0, stream>>>(d1, pw1T, z2);
    k_stats<<<512, 256, 0, stream>>>(z2, p2);
    k_params<<<1, 128, 0, stream>>>(p2, g1, b1);
    k_dw<<<6144, 256, 0, stream>>>(z2, p2, dw2, d2);   // overwrites pw1T (dead)
    k_tr<<<128, 256, 0, stream>>>(pw2, pw2T, 128);     // d1 (C) dead
    k_pw<128><<<dim3(192, 2, 2), 256, 0, stream>>>(d2, pw2T, z3);
    k_stats<<<512, 256, 0, stream>>>(z3, p3);
    k_params<<<1, 128, 0, stream>>>(p3, g2, b2);
    k_final<<<6144, 256, 0, stream>>>(z3, p3, out);
}